// Round 13
// baseline (8074.715 us; speedup 1.0000x reference)
//
#include <hip/hip_runtime.h>
#include <hip/hip_bf16.h>

typedef __bf16 bf16x8 __attribute__((ext_vector_type(8)));
typedef float f32x4 __attribute__((ext_vector_type(4)));
typedef unsigned short u16;

#define GLD_LDS16(gp, lp) __builtin_amdgcn_global_load_lds( \
    (const __attribute__((address_space(1))) unsigned int*)(gp), \
    (__attribute__((address_space(3))) unsigned int*)(lp), 16, 0, 0)

__device__ __forceinline__ float tanh_fast(float x) {
  float e = __expf(2.0f * x);
  return 1.0f - __fdividef(2.0f, e + 1.0f);
}

__device__ __forceinline__ u16 bf16_rn(float x) {
  union { float f; unsigned u; } v; v.f = x;
  unsigned r = v.u + 0x7fffu + ((v.u >> 16) & 1u);
  return (u16)(r >> 16);
}

// ---------------------------------------------------------------------------
// Fused GEMM: C[M,N] = A[M,K] (bf16 row-major) x Bt[N,K]^T (bf16 row-major)
// R13: B operand (weights W1t/W2t, 2MB, L2-resident) is NOT staged in LDS --
// fragments load straight from global to VGPR in the ks loop (16B/lane at
// row-stride K: each instr = 16 full 64B lines; compiler pipelines freely,
// no barrier dependency). Only A goes through LDS (T2 both-sides swizzle).
// Freed LDS doubles the A K-tile: GEMM-A BK=256 (2 drains), GEMM-B BK=512
// (4 drains); 64KB/block keeps 2 blocks/CU at grid 512.
// Ledger per K32/CU: A: MFMA 621 (bound) vs LDS 384 vs L2 242;
//                    B: LDS 192 (bound) vs MFMA 155 vs L2 121.
// Keeps: XCD m-band swizzle, T5 setprio, direct fragment epilogue (R12).
// MODE 0: out_bf = bf16(tanh(acc + bias + t*wt))
// MODE 1: v = 0.999*y + 0.001*z + h*(acc+bias); out32 = v; out_bf = v
// MODE 2: v = z + h*(acc+bias);                 out32 = v; out_bf = v
// ---------------------------------------------------------------------------
template <int BM, int BN, int BK, int K, int MODE, int NTL>
__global__ __launch_bounds__(256, 2)
void gemm_fused(const u16* __restrict__ A, const u16* __restrict__ Bt,
                const float* __restrict__ bias, const float* __restrict__ wt,
                float tval,
                const float* __restrict__ y_in, const float* __restrict__ z_in,
                float* __restrict__ out32, u16* __restrict__ out_bf, int N) {
  constexpr int NS = BK / 64;                 // 64-col A slabs
  constexpr int WTM = BM / 2, WTN = BN / 2;   // per-wave tile (2x2 wave grid)
  constexpr int FM = WTM / 16, FN = WTN / 16; // fragments per wave
  constexpr int ACH = BM * BK * 2 / 1024;     // 1KB A staging chunks
  constexpr int CPS_A = BM / 8;               // chunks per slab
  constexpr int MT = 4096 / BM;               // m-tiles total
  constexpr int MPX = MT / 8;                 // m-tiles per XCD

  __shared__ u16 As[NS * BM * 64];  // [slab][row][64]  (A only)

  const int tid = threadIdx.x;
  const int wave = tid >> 6;
  const int lane = tid & 63;
  const int wm = wave >> 1, wn = wave & 1;
  const int l15 = lane & 15, kg = lane >> 4;

  const int wg = blockIdx.x;
  const int xcd = wg & 7;
  const int j = wg >> 3;
  const int bm0 = (xcd * MPX + j / NTL) * BM;
  const int bn0 = (j % NTL) * BN;

  f32x4 acc[FM][FN];
#pragma unroll
  for (int m = 0; m < FM; ++m)
#pragma unroll
    for (int n = 0; n < FN; ++n) acc[m][n] = (f32x4){0.f, 0.f, 0.f, 0.f};

  const int sr = lane >> 3;                     // row within 8-row (1KB) chunk
  const int scs = ((lane & 7) ^ sr) * 8;        // PRE-SWIZZLED src col (A)
  const int rsw = (l15 & 7) << 3;               // read-side XOR (A)

  const u16* Ag = A + (size_t)bm0 * K;
  // Per-lane B base: row (bn0 + wn*WTN + l15), col kg*8.
  const u16* Bw = Bt + (size_t)(bn0 + wn * WTN + l15) * K + kg * 8;

  for (int kt = 0; kt < K / BK; ++kt) {
    const u16* Ak = Ag + (size_t)kt * BK;
#pragma unroll
    for (int i = 0; i < ACH / 4; ++i) {
      const int ch = wave + i * 4;
      const int kh = ch / CPS_A;   // slab index
      const int rg = ch % CPS_A;   // 8-row group
      GLD_LDS16(Ak + (size_t)(rg * 8 + sr) * K + kh * 64 + scs,
                (char*)As + ch * 1024);
    }
    __syncthreads();
#pragma unroll
    for (int ks = 0; ks < 2 * NS; ++ks) {
      const int kh = ks >> 1;
      const int kcA = ((ks & 1) * 32 + kg * 8) ^ rsw;       // swizzled A col
      const size_t kcB = (size_t)kt * BK + kh * 64 + (ks & 1) * 32;  // global B col
      bf16x8 af[FM], bfr[FN];
#pragma unroll
      for (int m = 0; m < FM; ++m)
        af[m] = *reinterpret_cast<const bf16x8*>(
            &As[(kh * BM + wm * WTM + m * 16 + l15) * 64 + kcA]);
#pragma unroll
      for (int n = 0; n < FN; ++n)
        bfr[n] = *reinterpret_cast<const bf16x8*>(Bw + (size_t)(n * 16) * K + kcB);
      __builtin_amdgcn_s_setprio(1);  // T5
#pragma unroll
      for (int m = 0; m < FM; ++m)
#pragma unroll
        for (int n = 0; n < FN; ++n)
          acc[m][n] =
              __builtin_amdgcn_mfma_f32_16x16x32_bf16(af[m], bfr[n], acc[m][n], 0, 0, 0);
      __builtin_amdgcn_s_setprio(0);
    }
    __syncthreads();
  }

  // Epilogue (R12). C/D layout: col = lane&15, row = (lane>>4)*4 + reg.
#pragma unroll
  for (int n = 0; n < FN; ++n) {
    const int col = bn0 + wn * WTN + n * 16 + l15;
    const float bv = bias[col];
    const float wv = (MODE == 0) ? wt[col] : 0.f;
#pragma unroll
    for (int m = 0; m < FM; ++m) {
      const int row0 = bm0 + wm * WTM + m * 16 + kg * 4;
      if (MODE == 0) {
#pragma unroll
        for (int r = 0; r < 4; ++r) {
          const size_t idx = (size_t)(row0 + r) * N + col;
          const float x = acc[m][n][r] + bv + tval * wv;
          out_bf[idx] = bf16_rn(tanh_fast(x));
        }
      } else {
        float yv[4], zv[4];
#pragma unroll
        for (int r = 0; r < 4; ++r) {
          const size_t idx = (size_t)(row0 + r) * N + col;
          zv[r] = z_in[idx];
          if (MODE == 1) yv[r] = y_in[idx];
        }
#pragma unroll
        for (int r = 0; r < 4; ++r) {
          const size_t idx = (size_t)(row0 + r) * N + col;
          const float a = acc[m][n][r] + bv;
          const float v = (MODE == 1)
              ? 0.999f * yv[r] + 0.001f * zv[r] + 0.015625f * a
              : zv[r] + 0.015625f * a;
          out32[idx] = v;
          out_bf[idx] = bf16_rn(v);
        }
      }
    }
  }
}

// in: [R, C] f32  ->  out: [C, R] bf16
__global__ void transpose_bf16(const float* __restrict__ in, u16* __restrict__ out,
                               int R, int C) {
  __shared__ float tile[32][33];
  const int bx = blockIdx.x * 32;
  const int by = blockIdx.y * 32;
  const int tx = threadIdx.x, ty = threadIdx.y;  // 32 x 8
#pragma unroll
  for (int i = 0; i < 32; i += 8)
    tile[ty + i][tx] = in[(size_t)(by + ty + i) * C + (bx + tx)];
  __syncthreads();
#pragma unroll
  for (int i = 0; i < 32; i += 8)
    out[(size_t)(bx + ty + i) * R + (by + tx)] = bf16_rn(tile[tx][ty + i]);
}

__global__ void init_state(const float* __restrict__ y0, float* __restrict__ y32,
                           float* __restrict__ z32, u16* __restrict__ zbf, int n) {
  const int i = blockIdx.x * blockDim.x + threadIdx.x;
  if (i < n) {
    const float v = y0[i];
    y32[i] = v;
    z32[i] = v;
    zbf[i] = bf16_rn(v);
  }
}

extern "C" void kernel_launch(void* const* d_in, const int* in_sizes, int n_in,
                              void* d_out, int out_size, void* d_ws, size_t ws_size,
                              hipStream_t stream) {
  const float* y0 = (const float*)d_in[0];
  const float* W1 = (const float*)d_in[1];  // [512, 2048]
  const float* b1 = (const float*)d_in[2];  // [2048]
  const float* wt = (const float*)d_in[3];  // [2048]
  const float* W2 = (const float*)d_in[4];  // [2048, 512]
  const float* b2 = (const float*)d_in[5];  // [512]

  constexpr int B = 4096, D = 512, HID = 2048, NSTEP = 64;
  constexpr float Hh = 1.0f / 64.0f;

  char* ws = (char*)d_ws;
  u16* W1t = (u16*)ws; ws += (size_t)HID * D * 2;   // [2048][512] bf16
  u16* W2t = (u16*)ws; ws += (size_t)D * HID * 2;   // [512][2048] bf16
  u16* hid = (u16*)ws; ws += (size_t)B * HID * 2;   // [4096][2048] bf16
  float* z32 = (float*)ws; ws += (size_t)B * D * 4; // [4096][512] f32
  u16* ybf = (u16*)ws; ws += (size_t)B * D * 2;
  u16* zbf = (u16*)ws; ws += (size_t)B * D * 2;
  float* y32 = (float*)d_out;

  transpose_bf16<<<dim3(HID / 32, D / 32), dim3(32, 8), 0, stream>>>(W1, W1t, D, HID);
  transpose_bf16<<<dim3(D / 32, HID / 32), dim3(32, 8), 0, stream>>>(W2, W2t, HID, D);
  init_state<<<(B * D + 255) / 256, 256, 0, stream>>>(y0, y32, z32, zbf, B * D);

  for (int s = 0; s < NSTEP; ++s) {
    const float t0 = (float)s * Hh;
    const float t1 = (float)(s + 1) * Hh;
    // hidden = tanh(z @ W1 + b1 + t0*wt)   512 blocks (32 m-tiles x 16 n-tiles)
    gemm_fused<128, 128, 256, 512, 0, 16><<<512, 256, 0, stream>>>(
        zbf, W1t, b1, wt, t0, nullptr, nullptr, nullptr, hid, HID);
    // y = 0.999*y + 0.001*z + h*(hidden @ W2 + b2)   512 blocks (64 x 8)
    gemm_fused<64, 64, 512, 2048, 1, 8><<<512, 256, 0, stream>>>(
        hid, W2t, b2, nullptr, 0.f, y32, z32, y32, ybf, D);
    // hidden = tanh(y @ W1 + b1 + t1*wt)
    gemm_fused<128, 128, 256, 512, 0, 16><<<512, 256, 0, stream>>>(
        ybf, W1t, b1, wt, t1, nullptr, nullptr, nullptr, hid, HID);
    // z = z + h*(hidden @ W2 + b2)
    gemm_fused<64, 64, 512, 2048, 2, 8><<<512, 256, 0, stream>>>(
        hid, W2t, b2, nullptr, 0.f, nullptr, z32, z32, zbf, D);
  }
}

// Round 14
// 5704.949 us; speedup vs baseline: 1.4154x; 1.4154x over previous
//
#include <hip/hip_runtime.h>
#include <hip/hip_bf16.h>

typedef __bf16 bf16x8 __attribute__((ext_vector_type(8)));
typedef float f32x4 __attribute__((ext_vector_type(4)));
typedef unsigned short u16;
typedef u16 u16x8 __attribute__((ext_vector_type(8)));

#define GLD_LDS16(gp, lp) __builtin_amdgcn_global_load_lds( \
    (const __attribute__((address_space(1))) unsigned int*)(gp), \
    (__attribute__((address_space(3))) unsigned int*)(lp), 16, 0, 0)

__device__ __forceinline__ float tanh_fast(float x) {
  float e = __expf(2.0f * x);
  return 1.0f - __fdividef(2.0f, e + 1.0f);
}

__device__ __forceinline__ u16 bf16_rn(float x) {
  union { float f; unsigned u; } v; v.f = x;
  unsigned r = v.u + 0x7fffu + ((v.u >> 16) & 1u);
  return (u16)(r >> 16);
}

// ---------------------------------------------------------------------------
// GEMM-A (hidden) = R12 verbatim (proven 4207us): 128x128 tile, BK=128,
// single-buffer 2-barrier loop, T2 both-sides XOR swizzle, XCD m-band
// swizzle, T5 setprio, direct fragment epilogue (bias + t*wt + tanh -> bf16).
// ---------------------------------------------------------------------------
template <int BM, int BN, int BK, int K, int NTL>
__global__ __launch_bounds__(256, 2)
void gemm_hidden(const u16* __restrict__ A, const u16* __restrict__ Bt,
                 const float* __restrict__ bias, const float* __restrict__ wt,
                 float tval, u16* __restrict__ out_bf, int N) {
  constexpr int NS = BK / 64;
  constexpr int WTM = BM / 2, WTN = BN / 2;
  constexpr int FM = WTM / 16, FN = WTN / 16;
  constexpr int ACH = BM * BK * 2 / 1024;
  constexpr int BCH = BN * BK * 2 / 1024;
  constexpr int CPS_A = BM / 8;
  constexpr int CPS_B = BN / 8;
  constexpr int MPX = (4096 / BM) / 8;
  constexpr int NCH = ACH / 4;

  __shared__ u16 As[NS * BM * 64];
  __shared__ u16 Bs[NS * BN * 64];

  const int tid = threadIdx.x;
  const int wave = tid >> 6;
  const int lane = tid & 63;
  const int wm = wave >> 1, wn = wave & 1;
  const int l15 = lane & 15, kg = lane >> 4;

  const int wg = blockIdx.x;
  const int xcd = wg & 7;
  const int j = wg >> 3;
  const int bm0 = (xcd * MPX + j / NTL) * BM;
  const int bn0 = (j % NTL) * BN;

  f32x4 acc[FM][FN];
#pragma unroll
  for (int m = 0; m < FM; ++m)
#pragma unroll
    for (int n = 0; n < FN; ++n) acc[m][n] = (f32x4){0.f, 0.f, 0.f, 0.f};

  const int sr = lane >> 3;
  const int scs = ((lane & 7) ^ sr) * 8;
  const int rsw = (l15 & 7) << 3;

  const u16* Ag = A + (size_t)bm0 * K;
  const u16* Bg = Bt + (size_t)bn0 * K;

  for (int kt = 0; kt < K / BK; ++kt) {
    const u16* Ak = Ag + kt * BK;
    const u16* Bk = Bg + kt * BK;
#pragma unroll
    for (int i = 0; i < NCH; ++i) {
      {
        const int ch = wave + i * 4;
        const int kh = ch / CPS_A;
        const int rg = ch % CPS_A;
        GLD_LDS16(Ak + (size_t)(rg * 8 + sr) * K + kh * 64 + scs,
                  (char*)As + ch * 1024);
      }
      if (i < BCH / 4) {
        const int ch = wave + i * 4;
        const int kh = ch / CPS_B;
        const int rg = ch % CPS_B;
        GLD_LDS16(Bk + (size_t)(rg * 8 + sr) * K + kh * 64 + scs,
                  (char*)Bs + ch * 1024);
      }
    }
    __syncthreads();
#pragma unroll
    for (int ks = 0; ks < 2 * NS; ++ks) {
      const int kh = ks >> 1;
      const int kc = ((ks & 1) * 32 + kg * 8) ^ rsw;
      bf16x8 af[FM], bfr[FN];
#pragma unroll
      for (int m = 0; m < FM; ++m)
        af[m] = *reinterpret_cast<const bf16x8*>(
            &As[(kh * BM + wm * WTM + m * 16 + l15) * 64 + kc]);
#pragma unroll
      for (int n = 0; n < FN; ++n)
        bfr[n] = *reinterpret_cast<const bf16x8*>(
            &Bs[(kh * BN + wn * WTN + n * 16 + l15) * 64 + kc]);
      __builtin_amdgcn_s_setprio(1);
#pragma unroll
      for (int m = 0; m < FM; ++m)
#pragma unroll
        for (int n = 0; n < FN; ++n)
          acc[m][n] =
              __builtin_amdgcn_mfma_f32_16x16x32_bf16(af[m], bfr[n], acc[m][n], 0, 0, 0);
      __builtin_amdgcn_s_setprio(0);
    }
    __syncthreads();
  }

#pragma unroll
  for (int n = 0; n < FN; ++n) {
    const int col = bn0 + wn * WTN + n * 16 + l15;
    const float bv = bias[col] + tval * wt[col];
#pragma unroll
    for (int m = 0; m < FM; ++m) {
      const int row0 = bm0 + wm * WTM + m * 16 + kg * 4;
#pragma unroll
      for (int r = 0; r < 4; ++r)
        out_bf[(size_t)(row0 + r) * N + col] =
            bf16_rn(tanh_fast(acc[m][n][r] + bv));
    }
  }
}

// ---------------------------------------------------------------------------
// GEMM-B (state update), R14: B operand (W2, 2MB, L2-resident) is consumed
// DIRECTLY from global in MFMA-fragment-packed layout -- a wave's fragment
// load is 64 lanes x 16B CONTIGUOUS (1KB coalesced), fixing R13's
// 64-lines-per-instruction disaster. No B in LDS -> A-slab doubles to BK=512
// -> 4 drains (was 8); LDS pipe traffic halves. A path keeps T2 both-sides
// swizzle; XCD m-band swizzle; T5 setprio; R12 epilogue.
// Packed layout: P[((kb*NB + nb)*64 + lane)*8 + e] = W2[kb*32+(lane>>4)*8+e]
//                [nb*16 + (lane&15)]   (kb = k/32, nb = n/16)
// MODE 1: v = 0.999*y + 0.001*z + h*(acc+bias); out32 = v; out_bf = v
// MODE 2: v = z + h*(acc+bias);                 out32 = v; out_bf = v
// ---------------------------------------------------------------------------
template <int MODE>
__global__ __launch_bounds__(256, 2)
void gemm_update(const u16* __restrict__ A, const u16* __restrict__ Bp,
                 const float* __restrict__ bias,
                 const float* __restrict__ y_in, const float* __restrict__ z_in,
                 float* __restrict__ out32, u16* __restrict__ out_bf) {
  constexpr int BM = 64, BN = 64, BK = 512, K = 2048, N = 512, NTL = 8;
  constexpr int NS = BK / 64;           // 8 slabs
  constexpr int NT = K / BK;            // 4 K-tiles
  constexpr int ACH = BM * BK * 2 / 1024;  // 64 chunks
  constexpr int CPS = BM / 8;           // 8 chunks per slab
  constexpr int MPX = (4096 / BM) / 8;  // 8 m-tiles per XCD
  constexpr int NB = N / 16;            // 32

  __shared__ u16 As[NS * BM * 64];      // 64KB, A only

  const int tid = threadIdx.x;
  const int wave = tid >> 6;
  const int lane = tid & 63;
  const int wm = wave >> 1, wn = wave & 1;
  const int l15 = lane & 15, kg = lane >> 4;

  const int wg = blockIdx.x;
  const int xcd = wg & 7;
  const int j = wg >> 3;
  const int bm0 = (xcd * MPX + j / NTL) * BM;
  const int bn0 = (j % NTL) * BN;

  f32x4 acc[2][2];
#pragma unroll
  for (int m = 0; m < 2; ++m)
#pragma unroll
    for (int n = 0; n < 2; ++n) acc[m][n] = (f32x4){0.f, 0.f, 0.f, 0.f};

  const int sr = lane >> 3;
  const int scs = ((lane & 7) ^ sr) * 8;
  const int rsw = (l15 & 7) << 3;

  const u16* Ag = A + (size_t)bm0 * K;
  // Per-lane packed-B base: nb block (bn0/16 + wn*2), this lane's 16B slot.
  const u16* Bpw = Bp + ((size_t)(bn0 / 16 + wn * 2) * 64 + lane) * 8;

  for (int kt = 0; kt < NT; ++kt) {
    const u16* Ak = Ag + (size_t)kt * BK;
#pragma unroll
    for (int i = 0; i < ACH / 4; ++i) {
      const int ch = wave + i * 4;
      const int kh = ch / CPS;   // slab
      const int rg = ch % CPS;   // 8-row group
      GLD_LDS16(Ak + (size_t)(rg * 8 + sr) * K + kh * 64 + scs,
                (char*)As + ch * 1024);
    }
    __syncthreads();
#pragma unroll
    for (int ks = 0; ks < 2 * NS; ++ks) {
      const int kh = ks >> 1;
      const int kcA = ((ks & 1) * 32 + kg * 8) ^ rsw;
      const int kb = kt * (BK / 32) + ks;   // global 32-K block index
      bf16x8 af[2], bfr[2];
#pragma unroll
      for (int m = 0; m < 2; ++m)
        af[m] = *reinterpret_cast<const bf16x8*>(
            &As[(kh * BM + wm * 32 + m * 16 + l15) * 64 + kcA]);
#pragma unroll
      for (int n = 0; n < 2; ++n)
        bfr[n] = *reinterpret_cast<const bf16x8*>(
            Bpw + (size_t)(kb * NB + n) * 512);  // 64 lanes x 16B contiguous
      __builtin_amdgcn_s_setprio(1);
#pragma unroll
      for (int m = 0; m < 2; ++m)
#pragma unroll
        for (int n = 0; n < 2; ++n)
          acc[m][n] =
              __builtin_amdgcn_mfma_f32_16x16x32_bf16(af[m], bfr[n], acc[m][n], 0, 0, 0);
      __builtin_amdgcn_s_setprio(0);
    }
    __syncthreads();
  }

  // Epilogue (R12). C/D layout: col = lane&15, row = (lane>>4)*4 + reg.
#pragma unroll
  for (int n = 0; n < 2; ++n) {
    const int col = bn0 + wn * 32 + n * 16 + l15;
    const float bv = bias[col];
#pragma unroll
    for (int m = 0; m < 2; ++m) {
      const int row0 = bm0 + wm * 32 + m * 16 + kg * 4;
      float yv[4], zv[4];
#pragma unroll
      for (int r = 0; r < 4; ++r) {
        const size_t idx = (size_t)(row0 + r) * N + col;
        zv[r] = z_in[idx];
        if (MODE == 1) yv[r] = y_in[idx];
      }
#pragma unroll
      for (int r = 0; r < 4; ++r) {
        const size_t idx = (size_t)(row0 + r) * N + col;
        const float a = acc[m][n][r] + bv;
        const float v = (MODE == 1)
            ? 0.999f * yv[r] + 0.001f * zv[r] + 0.015625f * a
            : zv[r] + 0.015625f * a;
        out32[idx] = v;
        out_bf[idx] = bf16_rn(v);
      }
    }
  }
}

// Pack W [K][Nn] f32 row-major -> P fragment-packed bf16:
// P[((kb*NB + nb)*64 + kg*16 + l15)*8 + e] = W[(kb*32+kg*8+e)*Nn + nb*16+l15]
// Reads coalesced along n (fixed e); writes fully coalesced 16B per thread.
template <int K, int Nn>
__global__ void pack_w(const float* __restrict__ W, u16* __restrict__ P) {
  constexpr int NB = Nn / 16;
  const int t = blockIdx.x * 256 + threadIdx.x;
  if (t >= (K / 32) * 4 * NB * 16) return;
  const int l15 = t & 15;
  const int nb = (t >> 4) % NB;
  const int kg = (t >> 4) / NB % 4;
  const int kb = (t >> 4) / NB / 4;
  const int n = nb * 16 + l15;
  const int k0 = kb * 32 + kg * 8;
  u16x8 o;
#pragma unroll
  for (int e = 0; e < 8; ++e) o[e] = bf16_rn(W[(size_t)(k0 + e) * Nn + n]);
  *reinterpret_cast<u16x8*>(&P[((size_t)(kb * NB + nb) * 64 + kg * 16 + l15) * 8]) = o;
}

// in: [R, C] f32  ->  out: [C, R] bf16
__global__ void transpose_bf16(const float* __restrict__ in, u16* __restrict__ out,
                               int R, int C) {
  __shared__ float tile[32][33];
  const int bx = blockIdx.x * 32;
  const int by = blockIdx.y * 32;
  const int tx = threadIdx.x, ty = threadIdx.y;  // 32 x 8
#pragma unroll
  for (int i = 0; i < 32; i += 8)
    tile[ty + i][tx] = in[(size_t)(by + ty + i) * C + (bx + tx)];
  __syncthreads();
#pragma unroll
  for (int i = 0; i < 32; i += 8)
    out[(size_t)(bx + ty + i) * R + (by + tx)] = bf16_rn(tile[tx][ty + i]);
}

__global__ void init_state(const float* __restrict__ y0, float* __restrict__ y32,
                           float* __restrict__ z32, u16* __restrict__ zbf, int n) {
  const int i = blockIdx.x * blockDim.x + threadIdx.x;
  if (i < n) {
    const float v = y0[i];
    y32[i] = v;
    z32[i] = v;
    zbf[i] = bf16_rn(v);
  }
}

extern "C" void kernel_launch(void* const* d_in, const int* in_sizes, int n_in,
                              void* d_out, int out_size, void* d_ws, size_t ws_size,
                              hipStream_t stream) {
  const float* y0 = (const float*)d_in[0];
  const float* W1 = (const float*)d_in[1];  // [512, 2048]
  const float* b1 = (const float*)d_in[2];  // [2048]
  const float* wt = (const float*)d_in[3];  // [2048]
  const float* W2 = (const float*)d_in[4];  // [2048, 512]
  const float* b2 = (const float*)d_in[5];  // [512]

  constexpr int B = 4096, D = 512, HID = 2048, NSTEP = 64;
  constexpr float Hh = 1.0f / 64.0f;

  char* ws = (char*)d_ws;
  u16* W1t = (u16*)ws; ws += (size_t)HID * D * 2;   // [2048][512] bf16
  u16* W2p = (u16*)ws; ws += (size_t)D * HID * 2;   // fragment-packed, 2MB
  u16* hid = (u16*)ws; ws += (size_t)B * HID * 2;   // [4096][2048] bf16
  float* z32 = (float*)ws; ws += (size_t)B * D * 4; // [4096][512] f32
  u16* ybf = (u16*)ws; ws += (size_t)B * D * 2;
  u16* zbf = (u16*)ws; ws += (size_t)B * D * 2;
  float* y32 = (float*)d_out;

  transpose_bf16<<<dim3(HID / 32, D / 32), dim3(32, 8), 0, stream>>>(W1, W1t, D, HID);
  pack_w<HID, D><<<(HID / 32) * 4 * (D / 16) * 16 / 256, 256, 0, stream>>>(W2, W2p);
  init_state<<<(B * D + 255) / 256, 256, 0, stream>>>(y0, y32, z32, zbf, B * D);

  for (int s = 0; s < NSTEP; ++s) {
    const float t0 = (float)s * Hh;
    const float t1 = (float)(s + 1) * Hh;
    // hidden = tanh(z @ W1 + b1 + t0*wt)   512 blocks (32 m-tiles x 16 n-tiles)
    gemm_hidden<128, 128, 128, 512, 16><<<512, 256, 0, stream>>>(
        zbf, W1t, b1, wt, t0, hid, HID);
    // y = 0.999*y + 0.001*z + h*(hidden @ W2 + b2)   512 blocks (64 x 8)
    gemm_update<1><<<512, 256, 0, stream>>>(hid, W2p, b2, y32, z32, y32, ybf);
    // hidden = tanh(y @ W1 + b1 + t1*wt)
    gemm_hidden<128, 128, 128, 512, 16><<<512, 256, 0, stream>>>(
        ybf, W1t, b1, wt, t1, hid, HID);
    // z = z + h*(hidden @ W2 + b2)
    gemm_update<2><<<512, 256, 0, stream>>>(hid, W2p, b2, nullptr, z32, z32, zbf);
  }
}

// Round 15
// 4225.080 us; speedup vs baseline: 1.9111x; 1.3503x over previous
//
#include <hip/hip_runtime.h>
#include <hip/hip_bf16.h>

typedef __bf16 bf16x8 __attribute__((ext_vector_type(8)));
typedef float f32x4 __attribute__((ext_vector_type(4)));
typedef unsigned short u16;

#define GLD_LDS16(gp, lp) __builtin_amdgcn_global_load_lds( \
    (const __attribute__((address_space(1))) unsigned int*)(gp), \
    (__attribute__((address_space(3))) unsigned int*)(lp), 16, 0, 0)

__device__ __forceinline__ float tanh_fast(float x) {
  float e = __expf(2.0f * x);
  return 1.0f - __fdividef(2.0f, e + 1.0f);
}

__device__ __forceinline__ u16 bf16_rn(float x) {
  union { float f; unsigned u; } v; v.f = x;
  unsigned r = v.u + 0x7fffu + ((v.u >> 16) & 1u);
  return (u16)(r >> 16);
}

// ---------------------------------------------------------------------------
// Fused GEMM: C[M,N] = A[M,K] (bf16 row-major) x Bt[N,K]^T (bf16 row-major)
// R15 == R12 (best, 4207us). Session ledger:
//   WINS: R3 2-blocks/CU for GEMM-B; R4 BK=128 + XCD m-band swizzle;
//         R6 BK=256 for GEMM-B; R8 T2 both-sides XOR bank-swizzle (-17%);
//         R12 setprio/launch_bounds/interleave/hoist bundle (-2%).
//   CLOSED BRANCHES (all regressed): LDS-staged epilogue (R5 +13%);
//     pipelining x3 (R7 +5%, R11 +33%, R2 +7%: __syncthreads drains vmcnt(0);
//     counted-vmcnt needs LDS we don't have at 2 blocks/CU);
//     occupancy re-tile (R9 +20%: kills fragment reuse);
//     wave K-split (R10 +6%: acc footprint + reduction overhead);
//     B-direct-from-L2 (R13 +92% uncoalesced, R14 +36% coalesced: LDS's
//     value is latency isolation, not just bandwidth).
// Composed floor ~60-66us/step vs measured ~65.7 -> at structural limit of
// this 4-dispatch-per-step decomposition.
// MODE 0: out_bf = bf16(tanh(acc + bias + t*wt))
// MODE 1: v = 0.999*y + 0.001*z + h*(acc+bias); out32 = v; out_bf = v
// MODE 2: v = z + h*(acc+bias);                 out32 = v; out_bf = v
// ---------------------------------------------------------------------------
template <int BM, int BN, int BK, int K, int MODE, int NTL>
__global__ __launch_bounds__(256, 2)
void gemm_fused(const u16* __restrict__ A, const u16* __restrict__ Bt,
                const float* __restrict__ bias, const float* __restrict__ wt,
                float tval,
                const float* __restrict__ y_in, const float* __restrict__ z_in,
                float* __restrict__ out32, u16* __restrict__ out_bf, int N) {
  constexpr int NS = BK / 64;                 // 64-col slabs
  constexpr int WTM = BM / 2, WTN = BN / 2;   // per-wave tile (2x2 wave grid)
  constexpr int FM = WTM / 16, FN = WTN / 16; // fragments per wave
  constexpr int ACH = BM * BK * 2 / 1024;     // 1KB staging chunks
  constexpr int BCH = BN * BK * 2 / 1024;
  constexpr int CPS_A = BM / 8;               // chunks per slab
  constexpr int CPS_B = BN / 8;
  constexpr int MT = 4096 / BM;               // m-tiles total
  constexpr int MPX = MT / 8;                 // m-tiles per XCD
  constexpr int NCH = ACH / 4;                // per-wave A chunks

  __shared__ u16 As[NS * BM * 64];  // [slab][row][64]
  __shared__ u16 Bs[NS * BN * 64];

  const int tid = threadIdx.x;
  const int wave = tid >> 6;
  const int lane = tid & 63;
  const int wm = wave >> 1, wn = wave & 1;
  const int l15 = lane & 15, kg = lane >> 4;

  const int wg = blockIdx.x;
  const int xcd = wg & 7;
  const int j = wg >> 3;
  const int bm0 = (xcd * MPX + j / NTL) * BM;
  const int bn0 = (j % NTL) * BN;

  f32x4 acc[FM][FN];
#pragma unroll
  for (int m = 0; m < FM; ++m)
#pragma unroll
    for (int n = 0; n < FN; ++n) acc[m][n] = (f32x4){0.f, 0.f, 0.f, 0.f};

  const int sr = lane >> 3;                     // row within 8-row (1KB) chunk
  const int scs = ((lane & 7) ^ sr) * 8;        // PRE-SWIZZLED src col
  const int rsw = (l15 & 7) << 3;               // read-side XOR

  const u16* Ag = A + (size_t)bm0 * K;
  const u16* Bg = Bt + (size_t)bn0 * K;

  for (int kt = 0; kt < K / BK; ++kt) {
    const u16* Ak = Ag + kt * BK;
    const u16* Bk = Bg + kt * BK;
    // Interleaved A/B chunk issue.
#pragma unroll
    for (int i = 0; i < NCH; ++i) {
      {
        const int ch = wave + i * 4;
        const int kh = ch / CPS_A;
        const int rg = ch % CPS_A;
        GLD_LDS16(Ak + (size_t)(rg * 8 + sr) * K + kh * 64 + scs,
                  (char*)As + ch * 1024);
      }
      if (i < BCH / 4) {
        const int ch = wave + i * 4;
        const int kh = ch / CPS_B;
        const int rg = ch % CPS_B;
        GLD_LDS16(Bk + (size_t)(rg * 8 + sr) * K + kh * 64 + scs,
                  (char*)Bs + ch * 1024);
      }
    }
    __syncthreads();
#pragma unroll
    for (int ks = 0; ks < 2 * NS; ++ks) {
      const int kh = ks >> 1;
      const int kc = ((ks & 1) * 32 + kg * 8) ^ rsw;  // swizzled read col
      bf16x8 af[FM], bfr[FN];
#pragma unroll
      for (int m = 0; m < FM; ++m)
        af[m] = *reinterpret_cast<const bf16x8*>(
            &As[(kh * BM + wm * WTM + m * 16 + l15) * 64 + kc]);
#pragma unroll
      for (int n = 0; n < FN; ++n)
        bfr[n] = *reinterpret_cast<const bf16x8*>(
            &Bs[(kh * BN + wn * WTN + n * 16 + l15) * 64 + kc]);
      __builtin_amdgcn_s_setprio(1);  // T5: favor MFMA cluster
#pragma unroll
      for (int m = 0; m < FM; ++m)
#pragma unroll
        for (int n = 0; n < FN; ++n)
          acc[m][n] =
              __builtin_amdgcn_mfma_f32_16x16x32_bf16(af[m], bfr[n], acc[m][n], 0, 0, 0);
      __builtin_amdgcn_s_setprio(0);
    }
    __syncthreads();
  }

  // Epilogue (direct fragment stores). C/D: col = lane&15, row = (lane>>4)*4 + reg.
#pragma unroll
  for (int n = 0; n < FN; ++n) {
    const int col = bn0 + wn * WTN + n * 16 + l15;
    const float bv = bias[col];
    const float wv = (MODE == 0) ? wt[col] : 0.f;
#pragma unroll
    for (int m = 0; m < FM; ++m) {
      const int row0 = bm0 + wm * WTM + m * 16 + kg * 4;
      if (MODE == 0) {
#pragma unroll
        for (int r = 0; r < 4; ++r) {
          const size_t idx = (size_t)(row0 + r) * N + col;
          const float x = acc[m][n][r] + bv + tval * wv;
          out_bf[idx] = bf16_rn(tanh_fast(x));
        }
      } else {
        float yv[4], zv[4];
#pragma unroll
        for (int r = 0; r < 4; ++r) {
          const size_t idx = (size_t)(row0 + r) * N + col;
          zv[r] = z_in[idx];
          if (MODE == 1) yv[r] = y_in[idx];
        }
#pragma unroll
        for (int r = 0; r < 4; ++r) {
          const size_t idx = (size_t)(row0 + r) * N + col;
          const float a = acc[m][n][r] + bv;
          const float v = (MODE == 1)
              ? 0.999f * yv[r] + 0.001f * zv[r] + 0.015625f * a
              : zv[r] + 0.015625f * a;
          out32[idx] = v;
          out_bf[idx] = bf16_rn(v);
        }
      }
    }
  }
}

// in: [R, C] f32  ->  out: [C, R] bf16
__global__ void transpose_bf16(const float* __restrict__ in, u16* __restrict__ out,
                               int R, int C) {
  __shared__ float tile[32][33];
  const int bx = blockIdx.x * 32;
  const int by = blockIdx.y * 32;
  const int tx = threadIdx.x, ty = threadIdx.y;  // 32 x 8
#pragma unroll
  for (int i = 0; i < 32; i += 8)
    tile[ty + i][tx] = in[(size_t)(by + ty + i) * C + (bx + tx)];
  __syncthreads();
#pragma unroll
  for (int i = 0; i < 32; i += 8)
    out[(size_t)(bx + ty + i) * R + (by + tx)] = bf16_rn(tile[tx][ty + i]);
}

__global__ void init_state(const float* __restrict__ y0, float* __restrict__ y32,
                           float* __restrict__ z32, u16* __restrict__ zbf, int n) {
  const int i = blockIdx.x * blockDim.x + threadIdx.x;
  if (i < n) {
    const float v = y0[i];
    y32[i] = v;
    z32[i] = v;
    zbf[i] = bf16_rn(v);
  }
}

extern "C" void kernel_launch(void* const* d_in, const int* in_sizes, int n_in,
                              void* d_out, int out_size, void* d_ws, size_t ws_size,
                              hipStream_t stream) {
  const float* y0 = (const float*)d_in[0];
  const float* W1 = (const float*)d_in[1];  // [512, 2048]
  const float* b1 = (const float*)d_in[2];  // [2048]
  const float* wt = (const float*)d_in[3];  // [2048]
  const float* W2 = (const float*)d_in[4];  // [2048, 512]
  const float* b2 = (const float*)d_in[5];  // [512]

  constexpr int B = 4096, D = 512, HID = 2048, NSTEP = 64;
  constexpr float Hh = 1.0f / 64.0f;

  char* ws = (char*)d_ws;
  u16* W1t = (u16*)ws; ws += (size_t)HID * D * 2;   // [2048][512] bf16
  u16* W2t = (u16*)ws; ws += (size_t)D * HID * 2;   // [512][2048] bf16
  u16* hid = (u16*)ws; ws += (size_t)B * HID * 2;   // [4096][2048] bf16
  float* z32 = (float*)ws; ws += (size_t)B * D * 4; // [4096][512] f32
  u16* ybf = (u16*)ws; ws += (size_t)B * D * 2;
  u16* zbf = (u16*)ws; ws += (size_t)B * D * 2;
  float* y32 = (float*)d_out;

  transpose_bf16<<<dim3(HID / 32, D / 32), dim3(32, 8), 0, stream>>>(W1, W1t, D, HID);
  transpose_bf16<<<dim3(D / 32, HID / 32), dim3(32, 8), 0, stream>>>(W2, W2t, HID, D);
  init_state<<<(B * D + 255) / 256, 256, 0, stream>>>(y0, y32, z32, zbf, B * D);

  for (int s = 0; s < NSTEP; ++s) {
    const float t0 = (float)s * Hh;
    const float t1 = (float)(s + 1) * Hh;
    // hidden = tanh(z @ W1 + b1 + t0*wt)   512 blocks (32 m-tiles x 16 n-tiles)
    gemm_fused<128, 128, 128, 512, 0, 16><<<512, 256, 0, stream>>>(
        zbf, W1t, b1, wt, t0, nullptr, nullptr, nullptr, hid, HID);
    // y = 0.999*y + 0.001*z + h*(hidden @ W2 + b2)   512 blocks (64 x 8)
    gemm_fused<64, 64, 256, 2048, 1, 8><<<512, 256, 0, stream>>>(
        hid, W2t, b2, nullptr, 0.f, y32, z32, y32, ybf, D);
    // hidden = tanh(y @ W1 + b1 + t1*wt)
    gemm_fused<128, 128, 128, 512, 0, 16><<<512, 256, 0, stream>>>(
        ybf, W1t, b1, wt, t1, nullptr, nullptr, nullptr, hid, HID);
    // z = z + h*(hidden @ W2 + b2)
    gemm_fused<64, 64, 256, 2048, 2, 8><<<512, 256, 0, stream>>>(
        hid, W2t, b2, nullptr, 0.f, nullptr, z32, z32, zbf, D);
  }
}